// Round 23
// baseline (43.666 us; speedup 1.0000x reference)
//
#include <hip/hip_runtime.h>
#include <hip/hip_bf16.h>
#include <stdint.h>

// Problem constants
#define BB 16
#define SS 512
#define TT 16
#define DD 128
#define CH 128                // s-rows per stage (r23: doubled from 64)
#define NCH (SS/CH)           // 4
#define LN_EPS 1e-5f

typedef __attribute__((ext_vector_type(8))) short short8;
typedef __attribute__((ext_vector_type(4))) float f32x4;

// HW packed f32->bf16 (RNE): dst.lo = src0, dst.hi = src1
static __device__ __forceinline__ uint32_t cvt_pk_bf16(float lo, float hi) {
    uint32_t r;
    asm("v_cvt_pk_bf16_f32 %0, %1, %2" : "=v"(r) : "v"(lo), "v"(hi));
    return r;
}

// LDS-ordering barrier: does NOT drain vmcnt.
#define BAR() do {                                            \
    asm volatile("s_waitcnt lgkmcnt(0)" ::: "memory");        \
    __builtin_amdgcn_s_barrier();                             \
    __builtin_amdgcn_s_barrier();                             \
} while (0)
#undef BAR
#define BAR() do {                                            \
    asm volatile("s_waitcnt lgkmcnt(0)" ::: "memory");        \
    __builtin_amdgcn_s_barrier();                             \
    asm volatile("" ::: "memory");                            \
} while (0)

// -----------------------------------------------------------------------------
// r12 structure with CH=128 (4 stages instead of 8): halves the number of
// barrier round-trips and per-stage fixed overheads (LN reduce startup,
// Hillis-Steele shuffle rounds, stage transitions), which r22 isolated as the
// residual cost (px prefetch was proven already-resident at VGPR=64).
//
// One block per (b,t) chain, 512 threads = 8 waves (2/SIMD).
// Wave w owns output cols [w*16,w*16+16) (gate) and +128 (hidden).
// Row permutation: LN writes s-row s to A-slot (mt*16+lhi*4+j) where
// s = lhi*32 + mt*4 + j (mt in [0,8)) -> each lane owns 32 CONSECUTIVE s-rows.
// Per stage (one barrier each):
//   phaseG(st): 8 m-tiles MFMA+activation -> Cc/Cv[32]; lane-local 32-row
//               prefix; cross-lhi Hillis-Steele (5 shuffles); 32 stores; hM.
//   phaseLN(st+1): 4 threads/row from register-prefetched x (32 f32/thread).
//   issuePx(st+2): register prefetch of next-next x chunk (32 VGPR).
// -----------------------------------------------------------------------------
__global__ __launch_bounds__(512, 2)
void fused_mingru(
    const float* __restrict__ x, const float* __restrict__ prevh,
    const float* __restrict__ gamma, const float* __restrict__ beta,
    const float* __restrict__ W, const float* __restrict__ bias,
    float* __restrict__ out, float* __restrict__ nexth)
{
    __shared__ __align__(16) unsigned char xnb[2][CH*256];  // 2 x 32 KB bf16 xn

    const int tid  = threadIdx.x;
    const int w    = tid >> 6;           // 0..7
    const int lane = tid & 63;
    const int l15  = lane & 15;
    const int lhi  = lane >> 4;

    const int bt = blockIdx.x;
    const size_t rowstride = (size_t)TT * DD;               // 2048
    const size_t base_bt   = ((size_t)(bt >> 4) * SS * TT + (bt & 15)) * DD;

    // ---- LN lane assignment: 4 threads per row, 32 floats each ----
    const int r_ln = tid >> 2;           // s-row 0..127 within chunk
    const int c4   = tid & 3;            // quarter of the row (8 x 16B chunks)
    // permuted A-slot: s = lhi*32 + mt*4 + j  ->  slot = mt*16 + lhi*4 + j
    const int slot_p = (((r_ln & 31) >> 2))*16 + (r_ln >> 5)*4 + (r_ln & 3);
    const int keyx   = slot_p & 7;
    const float* xp0 = x + base_bt + (size_t)r_ln * rowstride + c4*32;

    // ---- register prefetch of x chunk (32 VGPR) ----
    f32x4 px[8];
    auto issuePx = [&](int st) {
        const float* xp = xp0 + (size_t)st * CH * rowstride;
        #pragma unroll
        for (int q = 0; q < 8; ++q)
            px[q] = *(const f32x4*)(xp + q*4);
    };
    issuePx(0);   // latency hidden under the W-fragment build

    // ---- build W fragments + folded bias in-kernel ----
    short8 wfr[2][4];
    float  bs2[2];
    #pragma unroll
    for (int ni = 0; ni < 2; ++ni) {
        const int col = (ni ? 128 : 0) + w*16 + l15;
        float acc = 0.0f;
        #pragma unroll
        for (int kt = 0; kt < 4; ++kt) {
            union { short8 s8; uint32_t u[4]; } fr;
            #pragma unroll
            for (int p = 0; p < 4; ++p) {
                const int k0 = kt*32 + lhi*8 + 2*p;
                const float w0 = W[(size_t)k0*256 + col];
                const float w1 = W[(size_t)(k0+1)*256 + col];
                acc = fmaf(beta[k0],   w0, acc);
                acc = fmaf(beta[k0+1], w1, acc);
                fr.u[p] = cvt_pk_bf16(gamma[k0]*w0, gamma[k0+1]*w1);
            }
            wfr[ni][kt] = fr.s8;
        }
        acc += __shfl_xor(acc, 16);
        acc += __shfl_xor(acc, 32);
        bs2[ni] = bias[col] + acc;
    }

    // running h for this wave's 16 columns (replicated across lhi groups)
    float hM = prevh[(size_t)bt*128 + w*16 + l15];

    // ---- LN: consume px regs -> xnb[st&1] at permuted slot (swizzled) ----
    auto phaseLN = [&](int st) {
        float s1 = 0.f, s2 = 0.f;
        #pragma unroll
        for (int q = 0; q < 8; ++q) {
            s1 += px[q].x + px[q].y + px[q].z + px[q].w;
            s2 += px[q].x*px[q].x + px[q].y*px[q].y
                + px[q].z*px[q].z + px[q].w*px[q].w;
        }
        s1 += __shfl_xor(s1, 1); s2 += __shfl_xor(s2, 1);
        s1 += __shfl_xor(s1, 2); s2 += __shfl_xor(s2, 2);
        const float mu = s1 * (1.0f/128.0f);
        const float rs = rsqrtf(s2 * (1.0f/128.0f) - mu*mu + LN_EPS);
        unsigned char* row = xnb[st & 1] + slot_p*256;
        #pragma unroll
        for (int m = 0; m < 4; ++m) {
            union { short8 s8; uint32_t u[4]; } a;
            a.u[0] = cvt_pk_bf16((px[2*m].x  -mu)*rs, (px[2*m].y  -mu)*rs);
            a.u[1] = cvt_pk_bf16((px[2*m].z  -mu)*rs, (px[2*m].w  -mu)*rs);
            a.u[2] = cvt_pk_bf16((px[2*m+1].x-mu)*rs, (px[2*m+1].y-mu)*rs);
            a.u[3] = cvt_pk_bf16((px[2*m+1].z-mu)*rs, (px[2*m+1].w-mu)*rs);
            const int ci = c4*4 + m;                         // 16B chunk 0..15
            *(short8*)(row + ((ci ^ keyx) << 4)) = a.s8;
        }
    };

    // ---- GEMM + activation + stage-wide in-register scan + out stores ----
    auto phaseG = [&](int st) {
        const unsigned char* xb = xnb[st & 1];
        float Cc[32], Cv[32];            // s = lhi*32 + idx, idx = mt*4 + j
        #pragma unroll
        for (int mt = 0; mt < 8; ++mt) {
            const unsigned char* rowp = xb + (mt*16 + l15)*256;
            short8 af[4];
            #pragma unroll
            for (int kt = 0; kt < 4; ++kt) {
                const int c = (kt << 2) | lhi;
                af[kt] = *(const short8*)(rowp + ((c ^ (l15 & 7)) << 4));
            }
            f32x4 ag = (f32x4)(0.f), ah = (f32x4)(0.f);
            #pragma unroll
            for (int kt = 0; kt < 4; ++kt) {
                ag = __builtin_amdgcn_mfma_f32_16x16x32_bf16(af[kt], wfr[0][kt], ag, 0, 0, 0);
                ah = __builtin_amdgcn_mfma_f32_16x16x32_bf16(af[kt], wfr[1][kt], ah, 0, 0, 0);
            }
            #pragma unroll
            for (int j = 0; j < 4; ++j) {
                const float g  = ag[j] + bs2[0];
                const float hh = ah[j] + bs2[1];
                const float cc = 1.0f / (1.0f + __expf(g));
                const float ga = (hh >= 0.0f) ? (hh + 0.5f)
                                              : (1.0f / (1.0f + __expf(-hh)));
                Cc[mt*4 + j] = cc;
                Cv[mt*4 + j] = (1.0f - cc) * ga;
            }
        }
        #pragma unroll
        for (int i = 1; i < 32; ++i) {       // lane-local prefix, 32 rows
            Cv[i] = fmaf(Cc[i], Cv[i-1], Cv[i]);
            Cc[i] = Cc[i] * Cc[i-1];
        }
        float Ic = Cc[31], Iv = Cv[31];      // cross-lhi Hillis-Steele
        float pc = __shfl_up(Ic, 16), pv = __shfl_up(Iv, 16);
        if (lhi >= 1) { Iv = fmaf(Ic, pv, Iv); Ic *= pc; }
        pc = __shfl_up(Ic, 32); pv = __shfl_up(Iv, 32);
        if (lhi >= 2) { Iv = fmaf(Ic, pv, Iv); Ic *= pc; }
        float Ec = __shfl_up(Ic, 16), Ev = __shfl_up(Iv, 16);
        if (lhi == 0) { Ec = 1.0f; Ev = 0.0f; }
        const float Mc = __shfl(Ic, 48 + l15);
        const float Mv = __shfl(Iv, 48 + l15);
        const float hE = fmaf(Ec, hM, Ev);   // h before row lhi*32
        float* op = out + base_bt + (size_t)(st*CH + lhi*32) * rowstride + w*16 + l15;
        #pragma unroll
        for (int i = 0; i < 32; ++i)
            op[(size_t)i * rowstride] = fmaf(Cc[i], hE, Cv[i]);
        hM = fmaf(Mc, hM, Mv);
    };

    // ---- prologue: LN(0) (waits px0), prefetch x(1) ----
    phaseLN(0);
    issuePx(1);
    BAR();

    // ---- main: one barrier per stage (4 stages) ----
    for (int st = 0; st < NCH; ++st) {
        phaseG(st);
        if (st + 1 < NCH) {
            phaseLN(st + 1);                 // consumes px(st+1)
            if (st + 2 < NCH) issuePx(st + 2);
        }
        BAR();
    }

    if (lane < 16)
        nexth[(size_t)bt*128 + w*16 + lane] = hM;
}

extern "C" void kernel_launch(void* const* d_in, const int* in_sizes, int n_in,
                              void* d_out, int out_size, void* d_ws, size_t ws_size,
                              hipStream_t stream) {
    const float* x     = (const float*)d_in[0];
    const float* prevh = (const float*)d_in[1];
    const float* gamma = (const float*)d_in[2];
    const float* beta  = (const float*)d_in[3];
    const float* W     = (const float*)d_in[4];
    const float* bias  = (const float*)d_in[5];

    float* out   = (float*)d_out;
    float* nexth = out + (size_t)BB*SS*TT*DD;              // 16777216

    fused_mingru<<<BB*TT, 512, 0, stream>>>(x, prevh, gamma, beta, W, bias,
                                            out, nexth);
}